// Round 3
// baseline (45.265 us; speedup 1.0000x reference)
//
#include <hip/hip_runtime.h>
#include <hip/hip_bf16.h>

#define N_CENTERS 16

// Forward value of the soft-quantizer + straight-through estimator is
// numerically W_hard = center[argmin_m |x - center[m]|] (w_bias + W_soft
// cancels W_soft). We reproduce numpy's argmin EXACTLY: compare the same
// fp32 values fl(|fl(x - c[m])|) (abs folds into VOP3 src modifiers, so the
// compared bits are identical), and tie-break first-index-wins via
// "keep left unless right is STRICTLY smaller" at every tournament node
// (left subtree always holds the lower original indices).
//
// R2 post-mortem: serial 16-step scan was a VCC-serialized dependency chain
// (~1150 cy/wave) -> VALU-retirement-bound at 4.17 TB/s. Tournament tree:
// dep depth 16 -> 4, independent compare targets, 8 elements interleaved.

__device__ __forceinline__ float nearest_center(float xv, const float* __restrict__ cv)
{
    // Leaf round fused with diff computation: only 8 winners live at once.
    float wd[8], wc[8];
#pragma unroll
    for (int k = 0; k < 8; ++k) {
        float da = xv - cv[2 * k];
        float db = xv - cv[2 * k + 1];
        bool r = fabsf(db) < fabsf(da);     // strict: left (lower m) wins ties
        wd[k] = r ? db : da;
        wc[k] = r ? cv[2 * k + 1] : cv[2 * k];
    }
    float vd[4], vc[4];
#pragma unroll
    for (int k = 0; k < 4; ++k) {
        bool r = fabsf(wd[2 * k + 1]) < fabsf(wd[2 * k]);
        vd[k] = r ? wd[2 * k + 1] : wd[2 * k];
        vc[k] = r ? wc[2 * k + 1] : wc[2 * k];
    }
    float ud[2], uc[2];
#pragma unroll
    for (int k = 0; k < 2; ++k) {
        bool r = fabsf(vd[2 * k + 1]) < fabsf(vd[2 * k]);
        ud[k] = r ? vd[2 * k + 1] : vd[2 * k];
        uc[k] = r ? vc[2 * k + 1] : vc[2 * k];
    }
    bool r = fabsf(ud[1]) < fabsf(ud[0]);
    return r ? uc[1] : uc[0];
}

__global__ void __launch_bounds__(256) quantizer_kernel(
    const float* __restrict__ x,
    const float* __restrict__ center,
    float* __restrict__ out,
    int half)   // half = n/8; thread i handles float4 i and i+half
{
    // Centers: pin to VGPRs once (v_cndmask can read at most one SGPR, so
    // SGPR-resident centers would cost a v_mov per tournament node).
    float cv[N_CENTERS];
#pragma unroll
    for (int m = 0; m < N_CENTERS; ++m) {
        float s = center[m];                 // wave-uniform scalar load
        asm("v_mov_b32 %0, %1" : "=v"(cv[m]) : "s"(s));
    }

    int i = blockIdx.x * blockDim.x + threadIdx.x;
    if (i >= half) return;

    const float4* __restrict__ x4 = reinterpret_cast<const float4*>(x);
    float4* __restrict__ o4 = reinterpret_cast<float4*>(out);

    // Two independent, perfectly-coalesced loads issued up front (MLP=2).
    float4 va = x4[i];
    float4 vb = x4[i + half];

    float4 ra, rb;
    ra.x = nearest_center(va.x, cv);
    ra.y = nearest_center(va.y, cv);
    ra.z = nearest_center(va.z, cv);
    ra.w = nearest_center(va.w, cv);
    rb.x = nearest_center(vb.x, cv);
    rb.y = nearest_center(vb.y, cv);
    rb.z = nearest_center(vb.z, cv);
    rb.w = nearest_center(vb.w, cv);

    o4[i] = ra;
    o4[i + half] = rb;
}

extern "C" void kernel_launch(void* const* d_in, const int* in_sizes, int n_in,
                              void* d_out, int out_size, void* d_ws, size_t ws_size,
                              hipStream_t stream) {
    const float* x      = (const float*)d_in[0];
    const float* center = (const float*)d_in[1];
    float* out          = (float*)d_out;

    int n = in_sizes[0];          // 16*64*128*128 = 16,777,216
    int half = n / 8;             // 2,097,152 threads, 8 elements each

    const int block = 256;
    int grid = (half + block - 1) / block;   // 8192 blocks

    quantizer_kernel<<<grid, block, 0, stream>>>(x, center, out, half);
}

// Round 4
// 35.138 us; speedup vs baseline: 1.2882x; 1.2882x over previous
//
#include <hip/hip_runtime.h>
#include <hip/hip_bf16.h>
#include <math.h>

#define N_CENTERS 16
#define B_LUT 1024
#define EPS_BAND 4e-6f

// Forward value of the soft-quantizer + STE is numerically
// W_hard = center[argmin_m |x - center[m]|]  (w_bias + W_soft cancels W_soft;
// measured absmax 0 in R1-R3).
//
// R3 post-mortem: exact 16-way compare is VALU-bound (~170 emitted ops/elem,
// VALUBusy 80%+, hbm 2.1 TB/s). New algorithm: nearest-center in 1D is a step
// function with 15 breakpoints (midpoints of SORTED centers). Bucket LUT over
// [min c, max c], 1024 buckets, entry = {mid, cLeft, cRight}:
//   mid = the single midpoint in/near the bucket (+INF: none, both cands equal;
//         NaN: >=2 midpoints -> always fall back).
// Fast path/elem: fma+clamp+cvt + 16B LUT load + cmp + select (~10 VALU).
// Exactness: midpoint rule can disagree with numpy's fp32 argmin(|x-c|) only
// within ~1.1e-6 of a midpoint (2^-24 rounding of the diffs + midpoint
// rounding). Lanes inside a 4e-6 band (check is NaN-true) trigger a whole-wave
// fallback to the bit-exact original-order scan (strict '<' = first-index
// tie-break, identical fp32 ops to numpy). ~1% of waves fall back.

__global__ void build_lut_kernel(const float* __restrict__ center,
                                 float4* __restrict__ lut /* [1 + B_LUT] */)
{
    int t = blockIdx.x * blockDim.x + threadIdx.x;
    if (t >= B_LUT) return;

    // Per-thread sort, static-index network (registers only; setup is tiny).
    float s[N_CENTERS];
#pragma unroll
    for (int m = 0; m < N_CENTERS; ++m) s[m] = center[m];
#pragma unroll
    for (int i = 0; i < N_CENTERS - 1; ++i)
#pragma unroll
        for (int j = 0; j < N_CENTERS - 1 - i; ++j) {
            float a = fminf(s[j], s[j + 1]);
            float b = fmaxf(s[j], s[j + 1]);
            s[j] = a; s[j + 1] = b;
        }

    float lo = s[0], hi = s[N_CENTERS - 1];
    float span = hi - lo;
    if (!(span > 0.f)) span = 1e-30f;
    float w = span / (float)B_LUT;
    float invw = (float)B_LUT / span;

    if (t == 0) lut[0] = make_float4(lo, invw, 0.f, 0.f);

    float bstart = lo + t * w;
    float bend = bstart + w;
    // Guard: covers fma/cvt bucket-routing slop (~1e-4*w) and the EPS band
    // spilling across bucket edges.
    float g = 0.01f * w + 2.0f * EPS_BAND;

    int cnt = 0, j0 = 0;
    float m0 = 0.f;
#pragma unroll
    for (int j = 0; j < N_CENTERS - 1; ++j) {
        float mj = 0.5f * (s[j] + s[j + 1]);
        if (mj >= bstart - g && mj < bend + g) {
            if (cnt == 0) { m0 = mj; j0 = j; }
            cnt++;
        }
    }

    float mid, cl, cr;
    if (cnt == 0) {
        // Nearest center for the whole bucket: k = #midpoints strictly left.
        int k = 0;
#pragma unroll
        for (int j = 0; j < N_CENTERS - 1; ++j)
            k += (0.5f * (s[j] + s[j + 1]) < bstart) ? 1 : 0;
        float ck = s[0];
#pragma unroll
        for (int j = 1; j < N_CENTERS; ++j) ck = (j == k) ? s[j] : ck;
        mid = INFINITY; cl = ck; cr = ck;   // x > INF false -> cl; band never hits
    } else if (cnt == 1) {
        float a = s[0], b = s[1];
#pragma unroll
        for (int j = 0; j < N_CENTERS - 1; ++j)
            if (j == j0) { a = s[j]; b = s[j + 1]; }
        mid = m0; cl = a; cr = b;
    } else {
        mid = __uint_as_float(0x7fc00000u);  // NaN: band check always true
        cl = 0.f; cr = 0.f;
    }
    lut[1 + t] = make_float4(mid, cl, cr, 0.f);
}

__global__ void __launch_bounds__(256) quantizer_kernel(
    const float* __restrict__ x,
    const float* __restrict__ center,
    const float4* __restrict__ lut,
    float* __restrict__ out,
    int n4)
{
    int i = blockIdx.x * blockDim.x + threadIdx.x;
    if (i >= n4) return;

    float4 hdr = lut[0];                  // L1-hot
    float lo = hdr.x, invw = hdr.y;

    const float4* __restrict__ x4 = reinterpret_cast<const float4*>(x);
    float4* __restrict__ o4 = reinterpret_cast<float4*>(out);

    float4 v = x4[i];
    float xs[4] = {v.x, v.y, v.z, v.w};

    // Bucket indices (short independent chains), then 4 independent LUT loads.
    int tt[4];
#pragma unroll
    for (int j = 0; j < 4; ++j) {
        float ft = (xs[j] - lo) * invw;
        ft = fminf(fmaxf(ft, 0.0f), (float)(B_LUT - 1));
        tt[j] = (int)ft;
    }
    float4 e[4];
#pragma unroll
    for (int j = 0; j < 4; ++j) e[j] = lut[1 + tt[j]];   // 16KB LUT, L1/L2-hot

    float r[4];
    bool danger = false;
#pragma unroll
    for (int j = 0; j < 4; ++j) {
        float mid = e[j].x;
        r[j] = (xs[j] > mid) ? e[j].z : e[j].y;
        danger |= !(fabsf(xs[j] - mid) >= EPS_BAND);   // NaN-true, INF-false
    }

    if (__any(danger)) {
        // Bit-exact numpy argmin: same fp32 ops, strict '<' = first-min wins.
#pragma unroll
        for (int j = 0; j < 4; ++j) {
            float xv = xs[j];
            float best = fabsf(xv - center[0]);
            float bc = center[0];
#pragma unroll
            for (int m = 1; m < N_CENTERS; ++m) {
                float d = fabsf(xv - center[m]);
                bool lt = d < best;
                best = lt ? d : best;
                bc = lt ? center[m] : bc;
            }
            r[j] = bc;
        }
    }

    o4[i] = make_float4(r[0], r[1], r[2], r[3]);
}

extern "C" void kernel_launch(void* const* d_in, const int* in_sizes, int n_in,
                              void* d_out, int out_size, void* d_ws, size_t ws_size,
                              hipStream_t stream) {
    const float* x      = (const float*)d_in[0];
    const float* center = (const float*)d_in[1];
    float* out          = (float*)d_out;
    float4* lut         = (float4*)d_ws;   // (1 + 1024) * 16B = 16.4 KB

    int n = in_sizes[0];          // 16*64*128*128 = 16,777,216
    int n4 = n / 4;               // 4,194,304 float4s

    build_lut_kernel<<<B_LUT / 256, 256, 0, stream>>>(center, lut);

    const int block = 256;
    int grid = (n4 + block - 1) / block;   // 16384 blocks, one float4/thread
    quantizer_kernel<<<grid, block, 0, stream>>>(x, center, lut, out, n4);
}

// Round 5
// 31.071 us; speedup vs baseline: 1.4568x; 1.1309x over previous
//
#include <hip/hip_runtime.h>
#include <hip/hip_bf16.h>
#include <math.h>

#define N_CENTERS 16
#define B_LUT 1024
#define EPS_BAND 4e-6f

// W_hard = center[argmin_m |x - center[m]|]  (STE forward; absmax 0 in R1-R4).
// Nearest-center in 1D = step function with 15 breakpoints (midpoints of
// sorted centers). Bucket LUT over [min c, max c]: entry {mid, cL, cR}
// (+INF mid: bucket interior, both cands equal; NaN mid: >=2 mids -> forced
// fallback). Lanes within EPS_BAND of mid (NaN-true check) -> whole-wave
// bit-exact numpy-order scan.
//
// R4 post-mortem: GLOBAL gathers from the 16KB LUT split into ~50 L1
// transactions each (random per-lane lines) -> TCP-bound ~30us. Fix: stage
// LUT in LDS; banked scatter costs ~1.6x conflict-free ds_read_b128 and the
// LDS pipe overlaps VMEM streaming -> HBM/L3-bound.

__global__ void build_lut_kernel(const float* __restrict__ center,
                                 float4* __restrict__ lut /* [1 + B_LUT] */)
{
    int t = blockIdx.x * blockDim.x + threadIdx.x;
    if (t >= B_LUT) return;

    float s[N_CENTERS];
#pragma unroll
    for (int m = 0; m < N_CENTERS; ++m) s[m] = center[m];
#pragma unroll
    for (int i = 0; i < N_CENTERS - 1; ++i)
#pragma unroll
        for (int j = 0; j < N_CENTERS - 1 - i; ++j) {
            float a = fminf(s[j], s[j + 1]);
            float b = fmaxf(s[j], s[j + 1]);
            s[j] = a; s[j + 1] = b;
        }

    float lo = s[0], hi = s[N_CENTERS - 1];
    float span = hi - lo;
    if (!(span > 0.f)) span = 1e-30f;
    float w = span / (float)B_LUT;
    float invw = (float)B_LUT / span;

    if (t == 0) lut[0] = make_float4(lo, invw, 0.f, 0.f);

    float bstart = lo + t * w;
    float bend = bstart + w;
    float g = 0.01f * w + 2.0f * EPS_BAND;   // cvt-routing slop + band spill

    int cnt = 0, j0 = 0;
    float m0 = 0.f;
#pragma unroll
    for (int j = 0; j < N_CENTERS - 1; ++j) {
        float mj = 0.5f * (s[j] + s[j + 1]);
        if (mj >= bstart - g && mj < bend + g) {
            if (cnt == 0) { m0 = mj; j0 = j; }
            cnt++;
        }
    }

    float mid, cl, cr;
    if (cnt == 0) {
        int k = 0;
#pragma unroll
        for (int j = 0; j < N_CENTERS - 1; ++j)
            k += (0.5f * (s[j] + s[j + 1]) < bstart) ? 1 : 0;
        float ck = s[0];
#pragma unroll
        for (int j = 1; j < N_CENTERS; ++j) ck = (j == k) ? s[j] : ck;
        mid = INFINITY; cl = ck; cr = ck;
    } else if (cnt == 1) {
        float a = s[0], b = s[1];
#pragma unroll
        for (int j = 0; j < N_CENTERS - 1; ++j)
            if (j == j0) { a = s[j]; b = s[j + 1]; }
        mid = m0; cl = a; cr = b;
    } else {
        mid = __uint_as_float(0x7fc00000u);  // NaN: always fall back
        cl = 0.f; cr = 0.f;
    }
    lut[1 + t] = make_float4(mid, cl, cr, 0.f);
}

__global__ void __launch_bounds__(256) quantizer_kernel(
    const float* __restrict__ x,
    const float* __restrict__ center,
    const float4* __restrict__ lut,
    float* __restrict__ out,
    int h4)   // h4 = n4/2; thread i handles float4 i and i+h4
{
    __shared__ float4 slut[B_LUT];   // 16 KB -> LDS caps at 8 blocks/CU (fine)

    // Cooperative stage: 4 rounds of coalesced 16B loads, L2-hot after blk 0.
#pragma unroll
    for (int k = 0; k < B_LUT / 256; ++k)
        slut[threadIdx.x + 256 * k] = lut[1 + threadIdx.x + 256 * k];
    __syncthreads();

    float4 hdr = lut[0];                  // wave-uniform s_load
    float lo = hdr.x, invw = hdr.y;

    int i = blockIdx.x * blockDim.x + threadIdx.x;
    if (i >= h4) return;

    const float4* __restrict__ x4 = reinterpret_cast<const float4*>(x);
    float4* __restrict__ o4 = reinterpret_cast<float4*>(out);

    // Two independent coalesced streams (MLP=2), 8 elements/thread.
    float4 va = x4[i];
    float4 vb = x4[i + h4];
    float xs[8] = {va.x, va.y, va.z, va.w, vb.x, vb.y, vb.z, vb.w};

    int tt[8];
#pragma unroll
    for (int j = 0; j < 8; ++j) {
        float ft = (xs[j] - lo) * invw;
        ft = fminf(fmaxf(ft, 0.0f), (float)(B_LUT - 1));
        tt[j] = (int)ft;
    }

    // 8 independent banked LDS gathers (ds_read_b128), ~1.6x conflict cost.
    float4 e[8];
#pragma unroll
    for (int j = 0; j < 8; ++j) e[j] = slut[tt[j]];

    float r[8];
    bool danger = false;
#pragma unroll
    for (int j = 0; j < 8; ++j) {
        float mid = e[j].x;
        r[j] = (xs[j] > mid) ? e[j].z : e[j].y;
        danger |= !(fabsf(xs[j] - mid) >= EPS_BAND);   // NaN-true, INF-false
    }

    if (__any(danger)) {
        // Bit-exact numpy argmin: same fp32 ops, strict '<' = first-min wins.
#pragma unroll
        for (int j = 0; j < 8; ++j) {
            float xv = xs[j];
            float best = fabsf(xv - center[0]);
            float bc = center[0];
#pragma unroll
            for (int m = 1; m < N_CENTERS; ++m) {
                float d = fabsf(xv - center[m]);
                bool lt = d < best;
                best = lt ? d : best;
                bc = lt ? center[m] : bc;
            }
            r[j] = bc;
        }
    }

    o4[i]      = make_float4(r[0], r[1], r[2], r[3]);
    o4[i + h4] = make_float4(r[4], r[5], r[6], r[7]);
}

extern "C" void kernel_launch(void* const* d_in, const int* in_sizes, int n_in,
                              void* d_out, int out_size, void* d_ws, size_t ws_size,
                              hipStream_t stream) {
    const float* x      = (const float*)d_in[0];
    const float* center = (const float*)d_in[1];
    float* out          = (float*)d_out;
    float4* lut         = (float4*)d_ws;   // (1 + 1024) * 16B = 16.4 KB

    int n = in_sizes[0];          // 16*64*128*128 = 16,777,216
    int n4 = n / 4;               // 4,194,304 float4s
    int h4 = n4 / 2;              // 2,097,152 threads

    build_lut_kernel<<<B_LUT / 256, 256, 0, stream>>>(center, lut);

    const int block = 256;
    int grid = (h4 + block - 1) / block;   // 8192 blocks
    quantizer_kernel<<<grid, block, 0, stream>>>(x, center, lut, out, h4);
}

// Round 6
// 30.668 us; speedup vs baseline: 1.4760x; 1.0131x over previous
//
#include <hip/hip_runtime.h>
#include <hip/hip_bf16.h>
#include <math.h>

#define N_CENTERS 16
#define B_LUT 1024

// W_hard = center[argmin_m |x - center[m]|]  (STE forward; absmax 0, R1-R5).
//
// Pair-LUT: bucket t over [lo+t*w, lo+(t+1)*w) stores the bracketing center
// pair (cA, cB) ORDERED BY ORIGINAL INDEX (8B). Decision per element is the
// exact numpy comparison restricted to the pair: pick cB iff
// fl(|x-cB|) < fl(|x-cA|) strictly; tie -> cA (lower original index) = numpy
// first-min tie-break. Valid because a single-midpoint bucket's pair answers
// exactly for all x in (m_{j-1}, m_{j+1}), which covers the bucket plus
// routing slop (~2e-4*w) by the 0.02*w guard band. Zero-midpoint bucket:
// (cK, cK). >=2 midpoints: NaN sentinel -> whole-wave bit-exact scan
// (expected 0 buckets at B=1024). NO eps band needed.
//
// R5 post-mortem: 16KB stage/block (134MB L2), b128 random gathers (~17us
// LDS pipe), band VALU -> 31us. This version: 8KB stage, b64 gathers, ~10
// VALU/elem, 4096 blocks x 4-stream MLP.

__global__ void build_lut_kernel(const float* __restrict__ center,
                                 float* __restrict__ ws)
{
    int t = blockIdx.x * blockDim.x + threadIdx.x;
    if (t >= B_LUT) return;

    // Per-thread value sort (static network, registers).
    float s[N_CENTERS];
#pragma unroll
    for (int m = 0; m < N_CENTERS; ++m) s[m] = center[m];
#pragma unroll
    for (int a = 0; a < N_CENTERS - 1; ++a)
#pragma unroll
        for (int j = 0; j < N_CENTERS - 1 - a; ++j) {
            float u = fminf(s[j], s[j + 1]);
            float v = fmaxf(s[j], s[j + 1]);
            s[j] = u; s[j + 1] = v;
        }

    float lo = s[0], hi = s[N_CENTERS - 1];
    float span = hi - lo;
    if (!(span > 0.f)) span = 1.f;          // degenerate: all entries (s0,s0)
    float w = span / (float)B_LUT;
    float invw = (float)B_LUT / span;
    float nb = -lo * invw;                  // ft = fma(x, invw, nb)

    if (t == 0) { ws[0] = lo; ws[1] = invw; ws[2] = nb; ws[3] = 0.f; }
    float2* lut = (float2*)(ws + 4);

    float mid[N_CENTERS - 1];
#pragma unroll
    for (int j = 0; j < N_CENTERS - 1; ++j) mid[j] = 0.5f * (s[j] + s[j + 1]);

    float bstart = lo + t * w;
    float bend = bstart + w;
    float g = 0.02f * w;                    // >> fma/cvt routing slop (~2e-4*w)

    int cnt = 0, j0 = 0;
#pragma unroll
    for (int j = 0; j < N_CENTERS - 1; ++j) {
        bool inb = (mid[j] >= bstart - g) && (mid[j] < bend + g);
        if (inb) { if (cnt == 0) j0 = j; cnt++; }
    }

    float ca, cb;
    if (cnt == 0) {
        int k = 0;
#pragma unroll
        for (int j = 0; j < N_CENTERS - 1; ++j) k += (mid[j] < bstart) ? 1 : 0;
        float ck = s[0];
#pragma unroll
        for (int j = 1; j < N_CENTERS; ++j) ck = (j == k) ? s[j] : ck;
        ca = ck; cb = ck;
    } else if (cnt == 1) {
        float a = s[0], b = s[1];
#pragma unroll
        for (int j = 0; j < N_CENTERS - 1; ++j)
            if (j == j0) { a = s[j]; b = s[j + 1]; }
        // First ORIGINAL index of each value (duplicates -> first occurrence).
        int ia = N_CENTERS - 1, ib = N_CENTERS - 1;
#pragma unroll
        for (int m = N_CENTERS - 1; m >= 0; --m) {
            float cm = center[m];
            if (cm == a) ia = m;
            if (cm == b) ib = m;
        }
        if (ia <= ib) { ca = a; cb = b; } else { ca = b; cb = a; }
    } else {
        ca = __uint_as_float(0x7fc00000u);  // NaN sentinel -> wave fallback
        cb = 0.f;
    }
    lut[t] = make_float2(ca, cb);
}

__global__ void __launch_bounds__(256) quantizer_kernel(
    const float* __restrict__ x,
    const float* __restrict__ center,
    const float* __restrict__ ws,
    float* __restrict__ out,
    int q)   // q = n4/4; thread i handles float4s i, i+q, i+2q, i+3q
{
    __shared__ __align__(16) float2 slut[B_LUT];   // 8 KB

    const float4* __restrict__ x4 = reinterpret_cast<const float4*>(x);
    float4* __restrict__ o4 = reinterpret_cast<float4*>(out);

    int i = blockIdx.x * blockDim.x + threadIdx.x;   // grid is exact: i < q

    // Issue all 4 independent stream loads up front (MLP=4).
    float4 v0 = x4[i];
    float4 v1 = x4[i + q];
    float4 v2 = x4[i + 2 * q];
    float4 v3 = x4[i + 3 * q];

    // Stage 8KB LUT: 2 coalesced float4 rounds (L2-hot after first blocks).
    const float4* __restrict__ g4 = reinterpret_cast<const float4*>(ws + 4);
    float4* s4 = reinterpret_cast<float4*>(slut);
    s4[threadIdx.x] = g4[threadIdx.x];
    s4[threadIdx.x + 256] = g4[threadIdx.x + 256];

    float invw = ws[1];   // wave-uniform s_loads
    float nb = ws[2];
    __syncthreads();

    float xs[16] = {v0.x, v0.y, v0.z, v0.w, v1.x, v1.y, v1.z, v1.w,
                    v2.x, v2.y, v2.z, v2.w, v3.x, v3.y, v3.z, v3.w};

    float r[16];
    bool bad = false;
#pragma unroll
    for (int j = 0; j < 16; ++j) {
        float ft = fmaf(xs[j], invw, nb);
        ft = __builtin_amdgcn_fmed3f(ft, 0.f, (float)(B_LUT - 1));  // clamp
        int t = (int)ft;
        float2 e = slut[t];                 // random ds_read_b64
        float da = fabsf(xs[j] - e.x);      // exact numpy ops on the pair
        float db = fabsf(xs[j] - e.y);
        r[j] = (db < da) ? e.y : e.x;       // strict: tie -> cA (lower index)
        bad |= (e.x != e.x);                // NaN sentinel
    }

    if (__any(bad)) {
        // Bit-exact numpy argmin, original order, strict '<' first-min.
#pragma unroll
        for (int j = 0; j < 16; ++j) {
            float xv = xs[j];
            float best = fabsf(xv - center[0]);
            float bc = center[0];
#pragma unroll
            for (int m = 1; m < N_CENTERS; ++m) {
                float d = fabsf(xv - center[m]);
                bool lt = d < best;
                best = lt ? d : best;
                bc = lt ? center[m] : bc;
            }
            r[j] = bc;
        }
    }

    o4[i]         = make_float4(r[0],  r[1],  r[2],  r[3]);
    o4[i + q]     = make_float4(r[4],  r[5],  r[6],  r[7]);
    o4[i + 2 * q] = make_float4(r[8],  r[9],  r[10], r[11]);
    o4[i + 3 * q] = make_float4(r[12], r[13], r[14], r[15]);
}

extern "C" void kernel_launch(void* const* d_in, const int* in_sizes, int n_in,
                              void* d_out, int out_size, void* d_ws, size_t ws_size,
                              hipStream_t stream) {
    const float* x      = (const float*)d_in[0];
    const float* center = (const float*)d_in[1];
    float* out          = (float*)d_out;
    float* ws           = (float*)d_ws;    // 16B hdr + 1024*8B pairs = 8.2 KB

    int n = in_sizes[0];          // 16*64*128*128 = 16,777,216
    int n4 = n / 4;               // 4,194,304 float4s
    int q  = n4 / 4;              // 1,048,576 float4s per stream

    build_lut_kernel<<<B_LUT / 256, 256, 0, stream>>>(center, ws);

    const int block = 256;
    int grid = q / block;         // 4096 blocks, 16 elements/thread
    quantizer_kernel<<<grid, block, 0, stream>>>(x, center, ws, out, q);
}

// Round 8
// 27.904 us; speedup vs baseline: 1.6222x; 1.0991x over previous
//
#include <hip/hip_runtime.h>
#include <hip/hip_bf16.h>
#include <math.h>

#define N_CENTERS 16
#define B_LUT 256

typedef float nfloat4 __attribute__((ext_vector_type(4)));  // native vec for nt-store

// W_hard = center[argmin_m |x - center[m]|]  (STE forward; absmax 0, R1-R6).
//
// Fused single kernel (R6 post-mortem: separate build kernel cost ~5us of
// graph-serialized dispatch; three different inner loops all plateaued at
// ~31us). Each block builds its own 256-bucket pair-LUT in LDS (one bucket
// per thread; redundant per-thread 16-value sort is ~360 VALU, hidden under
// the 4 x-stream loads issued first). Bucket t stores the bracketing center
// pair (cA,cB) ordered by ORIGINAL index; per-element decision
// r = fl(|x-cB|) < fl(|x-cA|) ? cB : cA  is bit-identical to numpy's argmin
// restricted to the pair, and the pair provably contains numpy's winner for
// every x that routes to the bucket: single-midpoint buckets have validity
// margin 2*(g - slop) ~ 0.039*w ~ 9e-4, vs fp32 distance-rounding ~1.4e-6
// (600x safety), so no eps-band is needed. >=2 midpoints in a widened
// bucket -> NaN sentinel -> whole-wave bit-exact original-order scan (cold;
// reloads x to keep hot-path registers low). Ties at a midpoint pick cA =
// lower original index = numpy first-min.
//
// out is write-once/never-read: nontemporal stores keep its 67MB from
// evicting x in L2/L3 (R3 counters: x was only half L3-resident), so steady
// state HBM ~= writes only.

__device__ __forceinline__ void quant4(const float4 v,
                                       const float2* __restrict__ slut,
                                       float invw, float nb,
                                       nfloat4& rr, bool& bad)
{
    float xs[4] = {v.x, v.y, v.z, v.w};
    float r[4];
#pragma unroll
    for (int j = 0; j < 4; ++j) {
        float ft = fmaf(xs[j], invw, nb);
        ft = __builtin_amdgcn_fmed3f(ft, 0.f, (float)(B_LUT - 1));  // clamp
        int t = (int)ft;
        float2 e = slut[t];                 // random ds_read_b64, 2KB table
        float da = fabsf(xs[j] - e.x);      // exact numpy ops on the pair
        float db = fabsf(xs[j] - e.y);
        r[j] = (db < da) ? e.y : e.x;       // strict: tie -> cA (lower index)
        bad |= (e.x != e.x);                // NaN sentinel
    }
    rr = (nfloat4){r[0], r[1], r[2], r[3]};
}

__device__ __forceinline__ float4 exact4(const float4 v,
                                         const float* __restrict__ center)
{
    float xs[4] = {v.x, v.y, v.z, v.w};
    float r[4];
#pragma unroll
    for (int j = 0; j < 4; ++j) {
        float xv = xs[j];
        float best = fabsf(xv - center[0]);
        float bc = center[0];
#pragma unroll
        for (int m = 1; m < N_CENTERS; ++m) {
            float d = fabsf(xv - center[m]);
            bool lt = d < best;             // strict '<': first-min wins
            best = lt ? d : best;
            bc = lt ? center[m] : bc;
        }
        r[j] = bc;
    }
    return make_float4(r[0], r[1], r[2], r[3]);
}

__global__ void __launch_bounds__(256) quantizer_kernel(
    const float* __restrict__ x,
    const float* __restrict__ center,
    float* __restrict__ out,
    int q)   // q = n4/4; thread i handles float4s i, i+q, i+2q, i+3q
{
    __shared__ __align__(16) float2 slut[B_LUT];   // 2 KB

    const float4* __restrict__ x4 = reinterpret_cast<const float4*>(x);
    float4* __restrict__ o4 = reinterpret_cast<float4*>(out);
    nfloat4* __restrict__ o4n = reinterpret_cast<nfloat4*>(out);

    int i = blockIdx.x * blockDim.x + threadIdx.x;   // grid exact: i < q

    // Issue all 4 independent stream loads NOW; they fly during LUT build.
    float4 v0 = x4[i];
    float4 v1 = x4[i + q];
    float4 v2 = x4[i + 2 * q];
    float4 v3 = x4[i + 3 * q];

    // ---- per-thread LUT build: bucket t = threadIdx.x ----------------------
    float s[N_CENTERS];
#pragma unroll
    for (int m = 0; m < N_CENTERS; ++m) s[m] = center[m];  // wave-uniform
#pragma unroll
    for (int a = 0; a < N_CENTERS - 1; ++a)
#pragma unroll
        for (int j = 0; j < N_CENTERS - 1 - a; ++j) {
            float u = fminf(s[j], s[j + 1]);
            float vmx = fmaxf(s[j], s[j + 1]);
            s[j] = u; s[j + 1] = vmx;
        }

    float lo = s[0], hi = s[N_CENTERS - 1];
    float span = hi - lo;
    if (!(span > 0.f)) span = 1.f;          // degenerate: all-equal centers
    float w = span / (float)B_LUT;
    float invw = (float)B_LUT / span;
    float nb = -lo * invw;                  // ft = fma(x, invw, nb)

    {
        int t = threadIdx.x;
        float bstart = lo + t * w;
        float bend = bstart + w;
        float g = 0.02f * w;                // >> fma/cvt routing slop (~6e-5*w)

        float mid[N_CENTERS - 1];
#pragma unroll
        for (int j = 0; j < N_CENTERS - 1; ++j) mid[j] = 0.5f * (s[j] + s[j + 1]);

        int cnt = 0, j0 = 0;
#pragma unroll
        for (int j = 0; j < N_CENTERS - 1; ++j) {
            bool inb = (mid[j] >= bstart - g) && (mid[j] < bend + g);
            if (inb) { if (cnt == 0) j0 = j; cnt++; }
        }

        float ca, cb;
        if (cnt == 0) {
            int k = 0;
#pragma unroll
            for (int j = 0; j < N_CENTERS - 1; ++j) k += (mid[j] < bstart) ? 1 : 0;
            float ck = s[0];
#pragma unroll
            for (int j = 1; j < N_CENTERS; ++j) ck = (j == k) ? s[j] : ck;
            ca = ck; cb = ck;
        } else if (cnt == 1) {
            float a = s[0], b = s[1];
#pragma unroll
            for (int j = 0; j < N_CENTERS - 1; ++j)
                if (j == j0) { a = s[j]; b = s[j + 1]; }
            // First ORIGINAL index of each value (dups -> first occurrence).
            int ia = N_CENTERS - 1, ib = N_CENTERS - 1;
#pragma unroll
            for (int m = N_CENTERS - 1; m >= 0; --m) {
                float cm = center[m];
                if (cm == a) ia = m;
                if (cm == b) ib = m;
            }
            if (ia <= ib) { ca = a; cb = b; } else { ca = b; cb = a; }
        } else {
            ca = __uint_as_float(0x7fc00000u);  // NaN sentinel -> wave fallback
            cb = 0.f;
        }
        slut[t] = make_float2(ca, cb);
    }
    __syncthreads();
    // -----------------------------------------------------------------------

    bool bad = false;
    nfloat4 r0, r1, r2, r3;
    quant4(v0, slut, invw, nb, r0, bad);
    quant4(v1, slut, invw, nb, r1, bad);
    quant4(v2, slut, invw, nb, r2, bad);
    quant4(v3, slut, invw, nb, r3, bad);

    // Nontemporal: out is write-once/never-read -> don't evict x from L2/L3.
    __builtin_nontemporal_store(r0, &o4n[i]);
    __builtin_nontemporal_store(r1, &o4n[i + q]);
    __builtin_nontemporal_store(r2, &o4n[i + 2 * q]);
    __builtin_nontemporal_store(r3, &o4n[i + 3 * q]);

    if (__any(bad)) {
        // Cold path (only if a widened bucket held >=2 midpoints): reload x,
        // recompute all 16 bit-exactly, overwrite. Same-thread same-address
        // stores are program-ordered, so the exact values win.
        float4 e0 = exact4(x4[i], center);
        float4 e1 = exact4(x4[i + q], center);
        float4 e2 = exact4(x4[i + 2 * q], center);
        float4 e3 = exact4(x4[i + 3 * q], center);
        o4[i]         = e0;
        o4[i + q]     = e1;
        o4[i + 2 * q] = e2;
        o4[i + 3 * q] = e3;
    }
}

extern "C" void kernel_launch(void* const* d_in, const int* in_sizes, int n_in,
                              void* d_out, int out_size, void* d_ws, size_t ws_size,
                              hipStream_t stream) {
    const float* x      = (const float*)d_in[0];
    const float* center = (const float*)d_in[1];
    float* out          = (float*)d_out;

    int n = in_sizes[0];          // 16*64*128*128 = 16,777,216
    int n4 = n / 4;               // 4,194,304 float4s
    int q  = n4 / 4;              // 1,048,576 float4s per stream

    const int block = 256;
    int grid = q / block;         // 4096 blocks, 16 elements/thread
    quantizer_kernel<<<grid, block, 0, stream>>>(x, center, out, q);
}